// Round 5
// baseline (759.674 us; speedup 1.0000x reference)
//
#include <hip/hip_runtime.h>

typedef __attribute__((ext_vector_type(8))) short bf16x8;
typedef __attribute__((ext_vector_type(8))) _Float16 f16x8;
typedef __attribute__((ext_vector_type(2))) __fp16 fp16v2;
typedef __attribute__((ext_vector_type(4))) float f32x4;

#define DDIM 128
#define NADDR 4096
#define VDIM 512
#define NT 64
#define NITER (NADDR/NT)
#define LOG2E 1.44269504088896340736f

// pack hi16(lo)->low short, hi16(hi)->high short
__device__ __forceinline__ unsigned pkhi(float hi, float lo){
  return __builtin_amdgcn_perm(__float_as_uint(hi), __float_as_uint(lo), 0x07060302u);
}

__global__ __launch_bounds__(512, 4)
void soft_addr_kernel(const float* __restrict__ sel,
                      const float* __restrict__ bank,
                      const float* __restrict__ addr,
                      float* __restrict__ out)
{
  // XOR-swizzled layouts: element (row, c) lives at row*W + ((c>>3)^(row&7))*8 + (c&7).
  // Unpadded power-of-2 rows; swizzle spreads the 8-lane b128 phases across all
  // 8 bank-quads -> conflict-free frag reads AND staging writes.
  __shared__ __align__(16) _Float16 sK[64*128];   // K tile  [n][d]  fp16
  __shared__ __align__(16) short   sVt[128*64];   // V^T     [v][n]  bf16
  __shared__ __align__(16) short    sP[128*64];   // exp(S)  [m][n]  bf16
  __shared__ float sL[2][128];

  const int tid  = threadIdx.x;
  const int wave = tid >> 6;
  const int lane = tid & 63;
  const int quad = lane >> 4;
  const int l16  = lane & 15;
  const int key  = l16 & 7;

  const int bid  = blockIdx.x;
  const int vblk = bid & 3;          // 128-wide V slice
  const int mblk = bid >> 2;         // 128-row M tile
  const int m0 = mblk*128, v0 = vblk*128;

  const int swr = (wave >> 1) * 32;  // S/PV row band (32 rows)
  const int swc = (wave & 1) * 32;   // S col base (32 of 64)
  const int wn  = (wave & 1) * 64;   // PV col base (64 of 128)

  // ---- Q fragments (A layout), pre-scaled by log2(e), fp16, loop-invariant ----
  f16x8 aQ[2][4];
  #pragma unroll
  for (int mi = 0; mi < 2; ++mi){
    const float* q = sel + (size_t)(m0 + swr + 16*mi + l16) * DDIM + quad*8;
    #pragma unroll
    for (int ks = 0; ks < 4; ++ks){
      float4 a = *(const float4*)(q + 32*ks);
      float4 b = *(const float4*)(q + 32*ks + 4);
      f16x8 f;
      f[0]=(_Float16)(a.x*LOG2E); f[1]=(_Float16)(a.y*LOG2E);
      f[2]=(_Float16)(a.z*LOG2E); f[3]=(_Float16)(a.w*LOG2E);
      f[4]=(_Float16)(b.x*LOG2E); f[5]=(_Float16)(b.y*LOG2E);
      f[6]=(_Float16)(b.z*LOG2E); f[7]=(_Float16)(b.w*LOG2E);
      aQ[mi][ks] = f;
    }
  }

  f32x4 oAcc[2][4];
  const f32x4 fz = {0.f,0.f,0.f,0.f};
  #pragma unroll
  for (int i=0;i<2;++i)
    #pragma unroll
    for (int j=0;j<4;++j) oAcc[i][j]=fz;
  float lacc[2][4] = {{0.f,0.f,0.f,0.f},{0.f,0.f,0.f,0.f}};

  // staging maps
  const int ksr = tid >> 3;            // K row 0..63
  const int kc0 = (tid & 7) * 16;      // K col base (16 floats)
  const int kg0 = (tid & 7) * 2;       // K 16B-group base
  const int vc  = tid & 127;           // V column 0..127
  const int vt  = tid >> 7;            // 0..3
  const int vnb = vt * 16;             // V n-base

  // ---- preload K tile 0 into registers ----
  float4 kf[4];
  {
    const float* ksrc = addr + (size_t)ksr*DDIM + kc0;
    kf[0] = *(const float4*)(ksrc);
    kf[1] = *(const float4*)(ksrc+4);
    kf[2] = *(const float4*)(ksrc+8);
    kf[3] = *(const float4*)(ksrc+12);
  }

  for (int nt = 0; nt < NITER; ++nt){
    const int n0 = nt * NT;
    __syncthreads();   // A: all prev-iter LDS reads complete

    // ---- issue V loads for CURRENT tile (consumed after S phase) ----
    float vv[16];
    {
      const float* vsrc = bank + (size_t)(n0 + vnb)*VDIM + v0 + vc;
      #pragma unroll
      for (int j=0;j<16;++j) vv[j] = vsrc[(size_t)j*VDIM];
    }

    // ---- write prefetched K regs -> sK (swizzled) ----
    {
      union { f16x8 v; fp16v2 h[4]; } u0, u1;
      u0.h[0] = __builtin_amdgcn_cvt_pkrtz(kf[0].x, kf[0].y);
      u0.h[1] = __builtin_amdgcn_cvt_pkrtz(kf[0].z, kf[0].w);
      u0.h[2] = __builtin_amdgcn_cvt_pkrtz(kf[1].x, kf[1].y);
      u0.h[3] = __builtin_amdgcn_cvt_pkrtz(kf[1].z, kf[1].w);
      u1.h[0] = __builtin_amdgcn_cvt_pkrtz(kf[2].x, kf[2].y);
      u1.h[1] = __builtin_amdgcn_cvt_pkrtz(kf[2].z, kf[2].w);
      u1.h[2] = __builtin_amdgcn_cvt_pkrtz(kf[3].x, kf[3].y);
      u1.h[3] = __builtin_amdgcn_cvt_pkrtz(kf[3].z, kf[3].w);
      *(f16x8*)&sK[ksr*128 + (( kg0      ^ (ksr&7))<<3)] = u0.v;
      *(f16x8*)&sK[ksr*128 + (((kg0 + 1) ^ (ksr&7))<<3)] = u1.v;
    }

    // ---- prefetch K for NEXT iter ----
    {
      const int nn = (n0 + NT < NADDR) ? (n0 + NT) : n0;  // last iter: reload (harmless)
      const float* ksrc = addr + (size_t)(nn + ksr)*DDIM + kc0;
      kf[0] = *(const float4*)(ksrc);
      kf[1] = *(const float4*)(ksrc+4);
      kf[2] = *(const float4*)(ksrc+8);
      kf[3] = *(const float4*)(ksrc+12);
    }
    __syncthreads();   // B: sK visible

    // ---- S = Q.K^T : wave 32 rows x 32 cols, K=128 (fp16) ----
    f32x4 sAcc[2][2];
    sAcc[0][0]=fz; sAcc[0][1]=fz; sAcc[1][0]=fz; sAcc[1][1]=fz;
    #pragma unroll
    for (int ks=0; ks<4; ++ks){
      const int g = ((4*ks + quad) ^ key) << 3;
      f16x8 bK0 = *(const f16x8*)&sK[(swc      + l16)*128 + g];
      f16x8 bK1 = *(const f16x8*)&sK[(swc + 16 + l16)*128 + g];
      sAcc[0][0] = __builtin_amdgcn_mfma_f32_16x16x32_f16(aQ[0][ks], bK0, sAcc[0][0], 0,0,0);
      sAcc[0][1] = __builtin_amdgcn_mfma_f32_16x16x32_f16(aQ[0][ks], bK1, sAcc[0][1], 0,0,0);
      sAcc[1][0] = __builtin_amdgcn_mfma_f32_16x16x32_f16(aQ[1][ks], bK0, sAcc[1][0], 0,0,0);
      sAcc[1][1] = __builtin_amdgcn_mfma_f32_16x16x32_f16(aQ[1][ks], bK1, sAcc[1][1], 0,0,0);
    }

    // ---- P = 2^S, truncate bf16; pair adjacent cols via DPP; b32 writes ----
    #pragma unroll
    for (int mi=0; mi<2; ++mi)
      #pragma unroll
      for (int ni=0; ni<2; ++ni)
        #pragma unroll
        for (int r=0; r<4; ++r){
          float p = __builtin_amdgcn_exp2f(sAcc[mi][ni][r]);
          unsigned pu = __float_as_uint(p);
          lacc[mi][r] += __uint_as_float(pu & 0xffff0000u);
          // neighbor lane's p (lane^1) via DPP quad_perm(1,0,3,2) - VALU only
          unsigned pou = (unsigned)__builtin_amdgcn_mov_dpp((int)pu, 0xB1, 0xF, 0xF, true);
          if (!(l16 & 1)){
            const int m = swr + 16*mi + 4*quad + r;
            const int c = swc + 16*ni + l16;
            *(unsigned*)&sP[m*64 + ((((c>>3) ^ (m&7))<<3) | (c&7))] =
                __builtin_amdgcn_perm(pou, pu, 0x07060302u);
          }
        }

    // ---- pack + write V tile (loads have had the whole S phase to land) ----
    {
      uint4 pk0, pk1;
      pk0.x = pkhi(vv[1], vv[0]);  pk0.y = pkhi(vv[3],  vv[2]);
      pk0.z = pkhi(vv[5], vv[4]);  pk0.w = pkhi(vv[7],  vv[6]);
      pk1.x = pkhi(vv[9], vv[8]);  pk1.y = pkhi(vv[11], vv[10]);
      pk1.z = pkhi(vv[13],vv[12]); pk1.w = pkhi(vv[15], vv[14]);
      *(uint4*)&sVt[vc*64 + (((2*vt    ) ^ (vc&7))<<3)] = pk0;
      *(uint4*)&sVt[vc*64 + (((2*vt + 1) ^ (vc&7))<<3)] = pk1;
    }
    __syncthreads();   // C: sP + sVt visible

    // ---- O += P.V : wave 32 rows x 64 cols, K=64 (bf16) ----
    #pragma unroll
    for (int kg=0; kg<2; ++kg){
      const int g = ((4*kg + quad) ^ key) << 3;
      bf16x8 aP0 = *(const bf16x8*)&sP[(swr      + l16)*64 + g];
      bf16x8 aP1 = *(const bf16x8*)&sP[(swr + 16 + l16)*64 + g];
      #pragma unroll
      for (int jx=0; jx<4; ++jx){
        bf16x8 bV = *(const bf16x8*)&sVt[(wn + 16*jx + l16)*64 + g];
        oAcc[0][jx] = __builtin_amdgcn_mfma_f32_16x16x32_bf16(aP0, bV, oAcc[0][jx], 0,0,0);
        oAcc[1][jx] = __builtin_amdgcn_mfma_f32_16x16x32_bf16(aP1, bV, oAcc[1][jx], 0,0,0);
      }
    }
  }

  // ---- partial denominators (wave covered 32 of 64 cols per n-tile) ----
  #pragma unroll
  for (int mi=0; mi<2; ++mi)
    #pragma unroll
    for (int r=0;r<4;++r){
      float s = lacc[mi][r];
      s += __shfl_xor(s, 1);
      s += __shfl_xor(s, 2);
      s += __shfl_xor(s, 4);
      s += __shfl_xor(s, 8);
      if (l16 == 0) sL[wave & 1][swr + 16*mi + 4*quad + r] = s;
    }
  __syncthreads();

  // ---- epilogue: divide + store ----
  #pragma unroll
  for (int i=0;i<2;++i){
    #pragma unroll
    for (int r=0;r<4;++r){
      int row = swr + 16*i + 4*quad + r;
      float inv = 1.0f / (sL[0][row] + sL[1][row]);
      float* op = out + (size_t)(m0 + row)*VDIM + v0 + wn;
      #pragma unroll
      for (int jx=0;jx<4;++jx)
        op[16*jx + l16] = oAcc[i][jx][r] * inv;
    }
  }
}

extern "C" void kernel_launch(void* const* d_in, const int* in_sizes, int n_in,
                              void* d_out, int out_size, void* d_ws, size_t ws_size,
                              hipStream_t stream) {
  const float* sel  = (const float*)d_in[0];   // [8,2048,128]
  const float* bank = (const float*)d_in[1];   // [4096,512]
  const float* addr = (const float*)d_in[2];   // [4096,128]
  float* out = (float*)d_out;                  // [8,2048,512]
  dim3 grid(512), block(512);
  hipLaunchKernelGGL(soft_addr_kernel, grid, block, 0, stream, sel, bank, addr, out);
}

// Round 6
// 264.292 us; speedup vs baseline: 2.8744x; 2.8744x over previous
//
#include <hip/hip_runtime.h>

typedef __attribute__((ext_vector_type(8))) short bf16x8;
typedef __attribute__((ext_vector_type(8))) _Float16 f16x8;
typedef __attribute__((ext_vector_type(2))) __fp16 fp16v2;
typedef __attribute__((ext_vector_type(4))) float f32x4;

#define DDIM 128
#define NADDR 4096
#define VDIM 512
#define NT 64
#define NITER (NADDR/NT)
#define LOG2E 1.44269504088896340736f

// pack hi16(lo)->low short, hi16(hi)->high short
__device__ __forceinline__ unsigned pkhi(float hi, float lo){
  return __builtin_amdgcn_perm(__float_as_uint(hi), __float_as_uint(lo), 0x07060302u);
}

__global__ __launch_bounds__(512, 4)
void soft_addr_kernel(const float* __restrict__ sel,
                      const float* __restrict__ bank,
                      const float* __restrict__ addr,
                      float* __restrict__ out)
{
  // XOR-swizzled layouts: element (row, c) at row*W + ((c>>3)^(row&7))*8 + (c&7).
  // Power-of-2 rows; swizzle spreads each 8-lane b128 phase across all 8
  // bank-quads -> conflict-free frag reads and staging writes.
  __shared__ __align__(16) _Float16 sK[64*128];   // K tile  [n][d]  fp16
  __shared__ __align__(16) short   sVt[128*64];   // V^T     [v][n]  bf16
  __shared__ __align__(16) short    sP[128*64];   // exp(S)  [m][n]  bf16
  __shared__ float sL[2][128];

  const int tid  = threadIdx.x;
  const int wave = tid >> 6;
  const int lane = tid & 63;
  const int quad = lane >> 4;
  const int l16  = lane & 15;
  const int key  = l16 & 7;

  const int bid  = blockIdx.x;
  const int vblk = bid & 3;          // 128-wide V slice
  const int mblk = bid >> 2;         // 128-row M tile
  const int m0 = mblk*128, v0 = vblk*128;

  const int swr = (wave >> 1) * 32;  // S/PV row band (32 rows)
  const int swc = (wave & 1) * 32;   // S col base (32 of 64)
  const int wn  = (wave & 1) * 64;   // PV col base (64 of 128)

  // ---- Q fragments (A layout), pre-scaled by log2(e), fp16, loop-invariant ----
  f16x8 aQ[2][4];
  #pragma unroll
  for (int mi = 0; mi < 2; ++mi){
    const float* q = sel + (size_t)(m0 + swr + 16*mi + l16) * DDIM + quad*8;
    #pragma unroll
    for (int ks = 0; ks < 4; ++ks){
      float4 a = *(const float4*)(q + 32*ks);
      float4 b = *(const float4*)(q + 32*ks + 4);
      f16x8 f;
      f[0]=(_Float16)(a.x*LOG2E); f[1]=(_Float16)(a.y*LOG2E);
      f[2]=(_Float16)(a.z*LOG2E); f[3]=(_Float16)(a.w*LOG2E);
      f[4]=(_Float16)(b.x*LOG2E); f[5]=(_Float16)(b.y*LOG2E);
      f[6]=(_Float16)(b.z*LOG2E); f[7]=(_Float16)(b.w*LOG2E);
      aQ[mi][ks] = f;
    }
  }

  f32x4 oAcc[2][4];
  const f32x4 fz = {0.f,0.f,0.f,0.f};
  #pragma unroll
  for (int i=0;i<2;++i)
    #pragma unroll
    for (int j=0;j<4;++j) oAcc[i][j]=fz;
  float lacc[2][4] = {{0.f,0.f,0.f,0.f},{0.f,0.f,0.f,0.f}};

  // staging maps
  const int ksr = tid >> 3;            // K row 0..63
  const int kc0 = (tid & 7) * 16;      // K col base (16 floats)
  const int kg0 = (tid & 7) * 2;       // K 16B-group base
  const int vc  = tid & 127;           // V column 0..127
  const int vt  = tid >> 7;            // 0..3
  const int vnb = vt * 16;             // V n-base

  const float* kbase = addr + (size_t)ksr*DDIM + kc0;
  const float* vbase = bank + (size_t)vnb*VDIM + v0 + vc;

  for (int nt = 0; nt < NITER; ++nt){
    const int n0 = nt * NT;
    __syncthreads();   // A: all prev-iter LDS reads complete

    // ---- stage K tile (load -> pkrtz -> swizzled b128 writes, no buffering) ----
    {
      const float* ksrc = kbase + (size_t)n0*DDIM;
      float4 a = *(const float4*)(ksrc);
      float4 b = *(const float4*)(ksrc+4);
      float4 c = *(const float4*)(ksrc+8);
      float4 d = *(const float4*)(ksrc+12);
      union { f16x8 v; fp16v2 h[4]; } u0, u1;
      u0.h[0] = __builtin_amdgcn_cvt_pkrtz(a.x, a.y);
      u0.h[1] = __builtin_amdgcn_cvt_pkrtz(a.z, a.w);
      u0.h[2] = __builtin_amdgcn_cvt_pkrtz(b.x, b.y);
      u0.h[3] = __builtin_amdgcn_cvt_pkrtz(b.z, b.w);
      u1.h[0] = __builtin_amdgcn_cvt_pkrtz(c.x, c.y);
      u1.h[1] = __builtin_amdgcn_cvt_pkrtz(c.z, c.w);
      u1.h[2] = __builtin_amdgcn_cvt_pkrtz(d.x, d.y);
      u1.h[3] = __builtin_amdgcn_cvt_pkrtz(d.z, d.w);
      *(f16x8*)&sK[ksr*128 + (( kg0      ^ (ksr&7))<<3)] = u0.v;
      *(f16x8*)&sK[ksr*128 + (((kg0 + 1) ^ (ksr&7))<<3)] = u1.v;
    }
    // ---- stage V tile transposed (load 16 strided, pack, 2 swizzled b128 writes) ----
    {
      const float* vsrc = vbase + (size_t)n0*VDIM;
      float v[16];
      #pragma unroll
      for (int j=0;j<16;++j) v[j] = vsrc[(size_t)j*VDIM];
      uint4 pk0, pk1;
      pk0.x = pkhi(v[1], v[0]);  pk0.y = pkhi(v[3],  v[2]);
      pk0.z = pkhi(v[5], v[4]);  pk0.w = pkhi(v[7],  v[6]);
      pk1.x = pkhi(v[9], v[8]);  pk1.y = pkhi(v[11], v[10]);
      pk1.z = pkhi(v[13],v[12]); pk1.w = pkhi(v[15], v[14]);
      *(uint4*)&sVt[vc*64 + (((2*vt    ) ^ (vc&7))<<3)] = pk0;
      *(uint4*)&sVt[vc*64 + (((2*vt + 1) ^ (vc&7))<<3)] = pk1;
    }
    __syncthreads();   // B: sK + sVt visible

    // ---- S = Q.K^T + P = 2^S, split by ni to keep only 8 sAcc regs live ----
    #pragma unroll
    for (int ni=0; ni<2; ++ni){
      f32x4 sAcc[2];
      sAcc[0]=fz; sAcc[1]=fz;
      #pragma unroll
      for (int ks=0; ks<4; ++ks){
        const int g = ((4*ks + quad) ^ key) << 3;
        f16x8 bK = *(const f16x8*)&sK[(swc + 16*ni + l16)*128 + g];
        sAcc[0] = __builtin_amdgcn_mfma_f32_16x16x32_f16(aQ[0][ks], bK, sAcc[0], 0,0,0);
        sAcc[1] = __builtin_amdgcn_mfma_f32_16x16x32_f16(aQ[1][ks], bK, sAcc[1], 0,0,0);
      }
      #pragma unroll
      for (int mi=0; mi<2; ++mi)
        #pragma unroll
        for (int r=0; r<4; ++r){
          float p = __builtin_amdgcn_exp2f(sAcc[mi][r]);
          unsigned pu = __float_as_uint(p);
          lacc[mi][r] += __uint_as_float(pu & 0xffff0000u);
          // neighbor lane's p (lane^1) via DPP quad_perm(1,0,3,2) - VALU only
          unsigned pou = (unsigned)__builtin_amdgcn_mov_dpp((int)pu, 0xB1, 0xF, 0xF, true);
          if (!(l16 & 1)){
            const int m = swr + 16*mi + 4*quad + r;
            const int c = swc + 16*ni + l16;
            *(unsigned*)&sP[m*64 + ((((c>>3) ^ (m&7))<<3) | (c&7))] =
                __builtin_amdgcn_perm(pou, pu, 0x07060302u);
          }
        }
    }
    __syncthreads();   // C: sP visible

    // ---- O += P.V : wave 32 rows x 64 cols, K=64 (bf16) ----
    #pragma unroll
    for (int kg=0; kg<2; ++kg){
      const int g = ((4*kg + quad) ^ key) << 3;
      bf16x8 aP0 = *(const bf16x8*)&sP[(swr      + l16)*64 + g];
      bf16x8 aP1 = *(const bf16x8*)&sP[(swr + 16 + l16)*64 + g];
      #pragma unroll
      for (int jx=0; jx<4; ++jx){
        bf16x8 bV = *(const bf16x8*)&sVt[(wn + 16*jx + l16)*64 + g];
        oAcc[0][jx] = __builtin_amdgcn_mfma_f32_16x16x32_bf16(aP0, bV, oAcc[0][jx], 0,0,0);
        oAcc[1][jx] = __builtin_amdgcn_mfma_f32_16x16x32_bf16(aP1, bV, oAcc[1][jx], 0,0,0);
      }
    }
  }

  // ---- partial denominators (wave covered 32 of 64 cols per n-tile) ----
  #pragma unroll
  for (int mi=0; mi<2; ++mi)
    #pragma unroll
    for (int r=0;r<4;++r){
      float s = lacc[mi][r];
      s += __shfl_xor(s, 1);
      s += __shfl_xor(s, 2);
      s += __shfl_xor(s, 4);
      s += __shfl_xor(s, 8);
      if (l16 == 0) sL[wave & 1][swr + 16*mi + 4*quad + r] = s;
    }
  __syncthreads();

  // ---- epilogue: divide + store ----
  #pragma unroll
  for (int i=0;i<2;++i){
    #pragma unroll
    for (int r=0;r<4;++r){
      int row = swr + 16*i + 4*quad + r;
      float inv = 1.0f / (sL[0][row] + sL[1][row]);
      float* op = out + (size_t)(m0 + row)*VDIM + v0 + wn;
      #pragma unroll
      for (int jx=0;jx<4;++jx)
        op[16*jx + l16] = oAcc[i][jx][r] * inv;
    }
  }
}

extern "C" void kernel_launch(void* const* d_in, const int* in_sizes, int n_in,
                              void* d_out, int out_size, void* d_ws, size_t ws_size,
                              hipStream_t stream) {
  const float* sel  = (const float*)d_in[0];   // [8,2048,128]
  const float* bank = (const float*)d_in[1];   // [4096,512]
  const float* addr = (const float*)d_in[2];   // [4096,128]
  float* out = (float*)d_out;                  // [8,2048,512]
  dim3 grid(512), block(512);
  hipLaunchKernelGGL(soft_addr_kernel, grid, block, 0, stream, sel, bank, addr, out);
}